// Round 13
// baseline (155.509 us; speedup 1.0000x reference)
//
#include <hip/hip_runtime.h>

typedef unsigned short ushort_t;
typedef __bf16 bf16x8 __attribute__((ext_vector_type(8)));
typedef unsigned short ushortx8 __attribute__((ext_vector_type(8)));
typedef unsigned short ushortx4 __attribute__((ext_vector_type(4)));
typedef unsigned int uintx4 __attribute__((ext_vector_type(4)));
typedef float floatx4 __attribute__((ext_vector_type(4)));
typedef float floatx16 __attribute__((ext_vector_type(16)));

__device__ inline void load16_lds(const ushort_t* g, ushort_t* l) {
  __builtin_amdgcn_global_load_lds(
      (__attribute__((address_space(1))) void*)(g),
      (__attribute__((address_space(3))) void*)(l),
      16, 0, 0);
}

__device__ inline float bf2f(ushort_t u) {
  unsigned int v = ((unsigned int)u) << 16;
  return __builtin_bit_cast(float, v);
}

__device__ inline ushort_t f2bf(float f) {
  unsigned int u = __builtin_bit_cast(unsigned int, f);
  u += 0x7fffu + ((u >> 16) & 1u);
  return (ushort_t)(u >> 16);
}

__device__ inline bf16x8 ldfrag(const ushort_t* p) {
  return __builtin_bit_cast(bf16x8, *(const ushortx8*)p);
}

// pack two f32 -> one u32 of 2 bf16 (lo = first arg); no builtin on gfx950.
__device__ inline unsigned cvtpk_bf16(float lo, float hi) {
  unsigned r;
  asm("v_cvt_pk_bf16_f32 %0, %1, %2" : "=v"(r) : "v"(lo), "v"(hi));
  return r;
}

// exchange one 32-lane half of a with the complementary half of b
// (HK/m214-v22 arg order; verified on HW with the same crow layout).
__device__ inline void plswap(unsigned& a, unsigned& b) {
  asm("v_permlane32_swap_b32 %0, %1" : "+v"(a), "+v"(b));
}

// per-wave dtype sniff; P(wrong | fp32) ~= 0.55^64 ~= 4e-17.
__device__ inline bool sniff_f32(const ushort_t* x, int lane_off) {
  float v = fabsf(bf2f(x[lane_off]));
  bool big = !(v < 1e4f);
  return __ballot(big) != 0ull;
}

// ---------------------------------------------------------------------------
// Canonicalize inputs to bf16 (x, Wq, Wk, Wv) and fp32 biases; inline sniff.
// ---------------------------------------------------------------------------
__global__ __launch_bounds__(256) void convert_all(
    const void* __restrict__ x,
    const void* __restrict__ wq, const void* __restrict__ wk, const void* __restrict__ wv,
    const void* __restrict__ bq, const void* __restrict__ bk, const void* __restrict__ bv,
    ushort_t* __restrict__ xb, ushort_t* __restrict__ wqb,
    ushort_t* __restrict__ wkb, ushort_t* __restrict__ wvb,
    float* __restrict__ biasf, int* __restrict__ flag)
{
  const bool f32 = sniff_f32((const ushort_t*)x, (int)(threadIdx.x & 63));
  const int seg = blockIdx.y;
  if (seg == 4) {
    if (blockIdx.x == 0 && threadIdx.x == 0) *flag = f32 ? 1 : 0;
    const int i = blockIdx.x * 256 + threadIdx.x;
    if (i >= 1024) return;
    const void* bs[3] = {bq, bk, bv};
#pragma unroll
    for (int k = 0; k < 3; ++k)
      biasf[k * 1024 + i] = f32 ? ((const float*)bs[k])[i] : bf2f(((const ushort_t*)bs[k])[i]);
    return;
  }
  const void* src = (seg == 0) ? x : (seg == 1) ? wq : (seg == 2) ? wk : wv;
  ushort_t* dst   = (seg == 0) ? xb : (seg == 1) ? wqb : (seg == 2) ? wkb : wvb;
  const int n = (seg == 0) ? 4194304 : 1048576;
  const int i = (blockIdx.x * 256 + threadIdx.x) * 8;
  if (i >= n) return;
  if (f32) {
    const float* s = (const float*)src + i;
    ushortx8 o;
#pragma unroll
    for (int j = 0; j < 8; ++j) o[j] = f2bf(s[j]);
    *(ushortx8*)(dst + i) = o;
  } else {
    *(ushortx8*)(dst + i) = *(const ushortx8*)((const ushort_t*)src + i);
  }
}

// ---------------------------------------------------------------------------
// QKV projection: out = x @ W^T + b; Q scaled by log2(e)/sqrt(64).
// which==2 (V) writes DIRECTLY in transposed layout Vt(bh,hs,s).
// ---------------------------------------------------------------------------
__global__ __launch_bounds__(256, 2) void qkv_gemm(
    const ushort_t* __restrict__ x,
    const ushort_t* __restrict__ Wq, const ushort_t* __restrict__ Wk,
    const ushort_t* __restrict__ Wv, const float* __restrict__ biasf,
    ushort_t* __restrict__ Qo, ushort_t* __restrict__ Ko, ushort_t* __restrict__ Vt)
{
  __shared__ __attribute__((aligned(16))) ushort_t As[128 * 32];
  __shared__ __attribute__((aligned(16))) ushort_t Bs[128 * 32];

  const int which = blockIdx.z;
  const ushort_t* W = (which == 0) ? Wq : (which == 1) ? Wk : Wv;
  const float oscale = (which == 0) ? 0.18033688011112042f : 1.0f;

  const int n0 = blockIdx.x * 128;
  const int m0 = blockIdx.y * 128;

  const int tid  = threadIdx.x;
  const int wave = tid >> 6;
  const int lane = tid & 63;
  const int ln   = lane & 15;
  const int quad = lane >> 4;
  const int wm = (wave >> 1) * 64;
  const int wn = (wave & 1) * 64;

  floatx4 acc[4][4];
#pragma unroll
  for (int i = 0; i < 4; ++i)
#pragma unroll
    for (int j = 0; j < 4; ++j) acc[i][j] = floatx4{0.f, 0.f, 0.f, 0.f};

  const int c1 = tid, c2 = tid + 256;
  const ushort_t* ga1 = x + (m0 + (c1 >> 2)) * 1024 + (c1 & 3) * 8;
  const ushort_t* ga2 = x + (m0 + (c2 >> 2)) * 1024 + (c2 & 3) * 8;
  const ushort_t* gb1 = W + (n0 + (c1 >> 2)) * 1024 + (c1 & 3) * 8;
  const ushort_t* gb2 = W + (n0 + (c2 >> 2)) * 1024 + (c2 & 3) * 8;
  ushort_t* la1 = As + wave * 512;
  ushort_t* la2 = As + 2048 + wave * 512;
  ushort_t* lb1 = Bs + wave * 512;
  ushort_t* lb2 = Bs + 2048 + wave * 512;

  for (int kt = 0; kt < 1024; kt += 32) {
    __syncthreads();
    load16_lds(ga1 + kt, la1);
    load16_lds(ga2 + kt, la2);
    load16_lds(gb1 + kt, lb1);
    load16_lds(gb2 + kt, lb2);
    __syncthreads();

    bf16x8 af[4], bfr[4];
#pragma unroll
    for (int mi = 0; mi < 4; ++mi)
      af[mi] = ldfrag(As + (wm + mi * 16 + ln) * 32 + quad * 8);
#pragma unroll
    for (int ni = 0; ni < 4; ++ni)
      bfr[ni] = ldfrag(Bs + (wn + ni * 16 + ln) * 32 + quad * 8);
#pragma unroll
    for (int mi = 0; mi < 4; ++mi)
#pragma unroll
      for (int ni = 0; ni < 4; ++ni)
        acc[mi][ni] = __builtin_amdgcn_mfma_f32_16x16x32_bf16(af[mi], bfr[ni], acc[mi][ni], 0, 0, 0);
  }

  float bvv[4];
#pragma unroll
  for (int ni = 0; ni < 4; ++ni) bvv[ni] = biasf[which * 1024 + n0 + wn + ni * 16 + ln];

  if (which == 2) {
#pragma unroll
    for (int mi = 0; mi < 4; ++mi)
#pragma unroll
      for (int ni = 0; ni < 4; ++ni) {
        const int col = n0 + wn + ni * 16 + ln;
        const int row0 = m0 + wm + mi * 16 + quad * 4;
        const int b = row0 >> 11, s0 = row0 & 2047;
        const int h = col >> 6, hs = col & 63;
        ushortx4 pk;
#pragma unroll
        for (int r = 0; r < 4; ++r) pk[r] = f2bf(acc[mi][ni][r] + bvv[ni]);
        *(ushortx4*)(Vt + ((size_t)((b * 16 + h) * 64 + hs)) * 2048 + s0) = pk;
      }
  } else {
    ushort_t* out = (which == 0) ? Qo : Ko;
#pragma unroll
    for (int mi = 0; mi < 4; ++mi)
#pragma unroll
      for (int ni = 0; ni < 4; ++ni) {
        const int col = n0 + wn + ni * 16 + ln;
#pragma unroll
        for (int r = 0; r < 4; ++r) {
          const int row = m0 + wm + mi * 16 + quad * 4 + r;
          out[row * 1024 + col] = f2bf((acc[mi][ni][r] + bvv[ni]) * oscale);
        }
      }
  }
}

// ---------------------------------------------------------------------------
// Flash attention v21 — v20 (LDS-shared K/V, counted pipeline) with the sync
// structure reduced to ONE barrier + one vmcnt per tile:
//   prologue: STAGE(tile0 -> buf0)
//   loop t:  vmcnt(0) -> sched_barrier -> s_barrier
//              // own tile-t loads landed (issued a full tile ago, ~400cy of
//              // cover vs ~200cy L2); after barrier ALL waves' loads landed
//              // AND everyone finished compute(t-1) -> overwrite is safe.
//            STAGE(t+1 -> buf (t+1)&1)    // lands under compute(t)
//            COMPUTE(buf t&1)
// vs v20: removes the post-compute lgkmcnt(0) drain + second barrier.
// + s_setprio(1) around MFMA clusters (T5): 4 blocks/CU at different phases
// is the m218b/m191-positive regime (R8's null was the lockstep 1-block shell).
// One __syncthreads() added before the combine (v20 got it from its tail
// barrier).  Math/staging/swizzle/combine byte-identical to v19/v20.
// ---------------------------------------------------------------------------
__global__ __launch_bounds__(256) void flash21(
    const ushort_t* __restrict__ Q, const ushort_t* __restrict__ Kx,
    const ushort_t* __restrict__ Vt, void* __restrict__ out,
    const int* __restrict__ flag)
{
  __shared__ __attribute__((aligned(16))) ushort_t Kl[2][4096];  // [buf][row64 x unit8 x 8el]
  __shared__ __attribute__((aligned(16))) ushort_t Vl[2][4096];  // rows = d, cols = kv

  const bool f32o = (*flag != 0);
  const int tid  = threadIdx.x;
  const int wave = tid >> 6;          // 0..3
  const int lane = tid & 63;
  const int l31 = lane & 31;
  const int hi  = lane >> 5;
  const int qsub = wave & 1;          // which 32 q-rows
  const int kvh  = wave >> 1;         // which 32-kv half of each tile

#define CROW(r) (((r) & 3) + 8 * ((r) >> 2) + 4 * hi)

  // XCD-swizzled, big-chunk-first: 1024 blocks = 32 bh x 32 chunks of 64 rows.
  const int i = blockIdx.x;
  const int xcd = i & 7, j = i >> 3;
  const int bh = xcd * 4 + (j & 3);
  const int cc = 31 - (j >> 2);        // q-chunk 0..31, big first
  const int b = bh >> 4, h = bh & 15;
  const int qblk = cc * 64;
  const int qw = qblk + 32 * qsub;     // this wave's first q row
  const int nt = cc + 1;               // 64-kv tiles staged by the block

  const ushort_t* kbase = Kx + ((size_t)b * 2048) * 1024 + h * 64;
  const ushort_t* vbase = Vt + (size_t)bh * 64 * 2048;

  // ---- staging geometry: per wave, 4 x global_load_lds (1KB each).
  // dest is linear (base + lane*16B); source unit is XOR-pre-swizzled so the
  // LDS image is LDS[row][u] = G[row][u ^ (row&7)] (rule #21 both-sides).
  const int srow = 8 * wave + (lane >> 3);            // row for chunk 0
  const int sus  = (lane & 7) ^ (lane >> 3);          // swizzled source unit
  const ushort_t* kp = kbase + (size_t)srow * 1024 + sus * 8;
  const ushort_t* vp = vbase + (size_t)srow * 2048 + sus * 8;

#define STAGE(BUFI, KV0) do {                                                 \
    const ushort_t* kp_ = kp + (size_t)(KV0) * 1024;                          \
    const ushort_t* vp_ = vp + (KV0);                                         \
    load16_lds(kp_,                     &Kl[BUFI][(wave << 6) * 8]);          \
    load16_lds(kp_ + 32 * 1024,         &Kl[BUFI][2048 + (wave << 6) * 8]);   \
    load16_lds(vp_,                     &Vl[BUFI][(wave << 6) * 8]);          \
    load16_lds(vp_ + (size_t)32 * 2048, &Vl[BUFI][2048 + (wave << 6) * 8]);   \
  } while (0)

  // Q as B-operand: n=q=l31, k = s*16 + hi*8 + j  (8 contiguous d per load)
  bf16x8 qf[4];
#pragma unroll
  for (int s = 0; s < 4; ++s)
    qf[s] = ldfrag(Q + (size_t)(b * 2048 + qw + l31) * 1024 + h * 64 + s * 16 + hi * 8);

  floatx16 ot[2];
#pragma unroll
  for (int dq = 0; dq < 2; ++dq)
#pragma unroll
    for (int r = 0; r < 16; ++r) ot[dq][r] = 0.f;
  float li = 0.f;

  const int swz = l31 & 7;            // read-side row&7 for K (krow) and V (vrow)

  // pack 8 p-values (one 16-kv step) and feed both d-quadrants
#define PACK_PV(BUFI, PARR, SH, KSTEP) do {                                   \
    unsigned X_ = cvtpk_bf16(PARR[8 * (SH) + 0], PARR[8 * (SH) + 1]);         \
    unsigned Y_ = cvtpk_bf16(PARR[8 * (SH) + 2], PARR[8 * (SH) + 3]);         \
    unsigned Z_ = cvtpk_bf16(PARR[8 * (SH) + 4], PARR[8 * (SH) + 5]);         \
    unsigned W_ = cvtpk_bf16(PARR[8 * (SH) + 6], PARR[8 * (SH) + 7]);         \
    plswap(X_, Z_);                                                           \
    plswap(Y_, W_);                                                           \
    uintx4 u_ = {X_, Y_, Z_, W_};                                             \
    const bf16x8 pa_ = __builtin_bit_cast(bf16x8, u_);                        \
    const bf16x8 v0_ = ldfrag(&Vl[BUFI][(l31) * 64 + ((2 * (KSTEP) + hi) ^ swz) * 8]);        \
    const bf16x8 v1_ = ldfrag(&Vl[BUFI][(32 + l31) * 64 + ((2 * (KSTEP) + hi) ^ swz) * 8]);   \
    __builtin_amdgcn_s_setprio(1);                                            \
    ot[0] = __builtin_amdgcn_mfma_f32_32x32x16_bf16(pa_, v0_, ot[0], 0, 0, 0);\
    ot[1] = __builtin_amdgcn_mfma_f32_32x32x16_bf16(pa_, v1_, ot[1], 0, 0, 0);\
    __builtin_amdgcn_s_setprio(0);                                            \
  } while (0)

  // this wave's 32-kv half of tile at kv0: S-MFMA -> mask/exp -> li -> PV
#define COMPUTE(BUFI, KV0) do {                                               \
    const int krow_ = 32 * kvh + l31;                                         \
    bf16x8 kf0_ = ldfrag(&Kl[BUFI][krow_ * 64 + ((0 + hi) ^ swz) * 8]);       \
    bf16x8 kf1_ = ldfrag(&Kl[BUFI][krow_ * 64 + ((2 + hi) ^ swz) * 8]);       \
    bf16x8 kf2_ = ldfrag(&Kl[BUFI][krow_ * 64 + ((4 + hi) ^ swz) * 8]);       \
    bf16x8 kf3_ = ldfrag(&Kl[BUFI][krow_ * 64 + ((6 + hi) ^ swz) * 8]);       \
    floatx16 st_;                                                             \
    _Pragma("unroll")                                                         \
    for (int r = 0; r < 16; ++r) st_[r] = 0.f;                                \
    __builtin_amdgcn_s_setprio(1);                                            \
    st_ = __builtin_amdgcn_mfma_f32_32x32x16_bf16(kf0_, qf[0], st_, 0, 0, 0); \
    st_ = __builtin_amdgcn_mfma_f32_32x32x16_bf16(kf1_, qf[1], st_, 0, 0, 0); \
    st_ = __builtin_amdgcn_mfma_f32_32x32x16_bf16(kf2_, qf[2], st_, 0, 0, 0); \
    st_ = __builtin_amdgcn_mfma_f32_32x32x16_bf16(kf3_, qf[3], st_, 0, 0, 0); \
    __builtin_amdgcn_s_setprio(0);                                            \
    const int kvb_ = (KV0) + 32 * kvh;                                        \
    float p_[16];                                                             \
    if (kvb_ + 31 > qw) {                                                     \
      const int qg_ = qw + l31;                                               \
      _Pragma("unroll")                                                       \
      for (int r = 0; r < 16; ++r) {                                          \
        const int kva_ = kvb_ + CROW(r);                                      \
        const float e_ = __builtin_amdgcn_exp2f(st_[r]);                      \
        p_[r] = (kva_ > qg_) ? 0.f : e_;                                      \
      }                                                                       \
    } else {                                                                  \
      _Pragma("unroll")                                                       \
      for (int r = 0; r < 16; ++r) p_[r] = __builtin_amdgcn_exp2f(st_[r]);    \
    }                                                                         \
    float ls_ = 0.f;                                                          \
    _Pragma("unroll")                                                         \
    for (int r = 0; r < 16; ++r) ls_ += p_[r];                                \
    li += ls_;                                                                \
    PACK_PV(BUFI, p_, 0, 2 * kvh + 0);                                        \
    PACK_PV(BUFI, p_, 1, 2 * kvh + 1);                                        \
  } while (0)

  // ---- main loop: ONE barrier + one vmcnt per tile, stage-1-ahead ----
  STAGE(0, 0);
  for (int t = 0; t < nt; ++t) {
    // own outstanding staging loads (tile t, issued a full tile ago) landed
    asm volatile("s_waitcnt vmcnt(0)" ::: "memory");
    __builtin_amdgcn_sched_barrier(0);
    __builtin_amdgcn_s_barrier();
    // after barrier: all waves' tile-t loads landed; everyone done with t-1
    if (t + 1 < nt) STAGE((t + 1) & 1, (t + 1) * 64);
    const int kv0 = t * 64;
    if (kv0 + 32 * kvh <= qw + 31) COMPUTE(t & 1, kv0);
    cur_unused:;
  }

#undef STAGE
#undef PACK_PV
#undef COMPUTE

  // finalize li: lane l and l^32 hold complementary kv rows of the same q
  float lf = li + __shfl_xor(li, 32);

  // waves finish compute at different times; sync before reusing K/V LDS
  __syncthreads();

  // ---- kv-half combine through dead K/V LDS ----
  float* Sc = (float*)&Kl[0][0];   // 4096 floats: [qsub][32 q][64 d]
  float* Lc = (float*)&Vl[0][0];   // [0..63] li sums, [64..127] 1/li
  if (kvh == 1) {
#pragma unroll
    for (int dq = 0; dq < 2; ++dq)
#pragma unroll
      for (int r = 0; r < 16; ++r)
        Sc[qsub * 2048 + CROW(r) * 64 + 32 * dq + l31] = ot[dq][r];
    Lc[qsub * 32 + l31] = lf;      // both hi-halves write the same value
  }
  __syncthreads();
  if (kvh == 0) {
#pragma unroll
    for (int dq = 0; dq < 2; ++dq)
#pragma unroll
      for (int r = 0; r < 16; ++r)
        ot[dq][r] += Sc[qsub * 2048 + CROW(r) * 64 + 32 * dq + l31];
    lf += Lc[qsub * 32 + l31];
    Lc[64 + qsub * 32 + l31] = 1.0f / lf;

#pragma unroll
    for (int r = 0; r < 16; ++r) {
      const int q_ = qw + CROW(r);
      const float iv = Lc[64 + qsub * 32 + CROW(r)];
      if (f32o) {
        float* of = (float*)out;
#pragma unroll
        for (int dq = 0; dq < 2; ++dq)
          of[(size_t)(b * 2048 + q_) * 1024 + h * 64 + 32 * dq + l31] = ot[dq][r] * iv;
      } else {
        ushort_t* ob = (ushort_t*)out;
#pragma unroll
        for (int dq = 0; dq < 2; ++dq)
          ob[(size_t)(b * 2048 + q_) * 1024 + h * 64 + 32 * dq + l31] = f2bf(ot[dq][r] * iv);
      }
    }
  }
#undef CROW
}

// ---------------------------------------------------------------------------
extern "C" void kernel_launch(void* const* d_in, const int* in_sizes, int n_in,
                              void* d_out, int out_size, void* d_ws, size_t ws_size,
                              hipStream_t stream) {
  char* w = (char*)d_ws;
  int* flag = (int*)w;
  size_t off = 256;
  ushort_t* xb  = (ushort_t*)(w + off); off += (size_t)4194304 * 2;
  ushort_t* wqb = (ushort_t*)(w + off); off += (size_t)1048576 * 2;
  ushort_t* wkb = (ushort_t*)(w + off); off += (size_t)1048576 * 2;
  ushort_t* wvb = (ushort_t*)(w + off); off += (size_t)1048576 * 2;
  float* biasf  = (float*)(w + off);    off += (size_t)3 * 1024 * 4;
  ushort_t* Qw  = (ushort_t*)(w + off); off += (size_t)4194304 * 2;
  ushort_t* Kw  = (ushort_t*)(w + off); off += (size_t)4194304 * 2;
  ushort_t* Vtw = (ushort_t*)(w + off);

  convert_all<<<dim3(2048, 5), 256, 0, stream>>>(
      d_in[0], d_in[1], d_in[3], d_in[5], d_in[2], d_in[4], d_in[6],
      xb, wqb, wkb, wvb, biasf, flag);
  qkv_gemm<<<dim3(8, 32, 3), 256, 0, stream>>>(xb, wqb, wkb, wvb, biasf, Qw, Kw, Vtw);
  flash21<<<1024, 256, 0, stream>>>(Qw, Kw, Vtw, d_out, flag);
}

// Round 14
// 155.171 us; speedup vs baseline: 1.0022x; 1.0022x over previous
//
#include <hip/hip_runtime.h>

typedef unsigned short ushort_t;
typedef __bf16 bf16x8 __attribute__((ext_vector_type(8)));
typedef unsigned short ushortx8 __attribute__((ext_vector_type(8)));
typedef unsigned short ushortx4 __attribute__((ext_vector_type(4)));
typedef unsigned int uintx4 __attribute__((ext_vector_type(4)));
typedef float floatx4 __attribute__((ext_vector_type(4)));
typedef float floatx16 __attribute__((ext_vector_type(16)));

__device__ inline void load16_lds(const ushort_t* g, ushort_t* l) {
  __builtin_amdgcn_global_load_lds(
      (__attribute__((address_space(1))) void*)(g),
      (__attribute__((address_space(3))) void*)(l),
      16, 0, 0);
}

__device__ inline float bf2f(ushort_t u) {
  unsigned int v = ((unsigned int)u) << 16;
  return __builtin_bit_cast(float, v);
}

__device__ inline ushort_t f2bf(float f) {
  unsigned int u = __builtin_bit_cast(unsigned int, f);
  u += 0x7fffu + ((u >> 16) & 1u);
  return (ushort_t)(u >> 16);
}

__device__ inline bf16x8 ldfrag(const ushort_t* p) {
  return __builtin_bit_cast(bf16x8, *(const ushortx8*)p);
}

// pack two f32 -> one u32 of 2 bf16 (lo = first arg); no builtin on gfx950.
__device__ inline unsigned cvtpk_bf16(float lo, float hi) {
  unsigned r;
  asm("v_cvt_pk_bf16_f32 %0, %1, %2" : "=v"(r) : "v"(lo), "v"(hi));
  return r;
}

// exchange one 32-lane half of a with the complementary half of b
// (HK/m214-v22 arg order; verified on HW with the same crow layout).
__device__ inline void plswap(unsigned& a, unsigned& b) {
  asm("v_permlane32_swap_b32 %0, %1" : "+v"(a), "+v"(b));
}

// per-wave dtype sniff; P(wrong | fp32) ~= 0.55^64 ~= 4e-17.
__device__ inline bool sniff_f32(const ushort_t* x, int lane_off) {
  float v = fabsf(bf2f(x[lane_off]));
  bool big = !(v < 1e4f);
  return __ballot(big) != 0ull;
}

// ---------------------------------------------------------------------------
// Canonicalize inputs to bf16 (x, Wq, Wk, Wv) and fp32 biases; inline sniff.
// ---------------------------------------------------------------------------
__global__ __launch_bounds__(256) void convert_all(
    const void* __restrict__ x,
    const void* __restrict__ wq, const void* __restrict__ wk, const void* __restrict__ wv,
    const void* __restrict__ bq, const void* __restrict__ bk, const void* __restrict__ bv,
    ushort_t* __restrict__ xb, ushort_t* __restrict__ wqb,
    ushort_t* __restrict__ wkb, ushort_t* __restrict__ wvb,
    float* __restrict__ biasf, int* __restrict__ flag)
{
  const bool f32 = sniff_f32((const ushort_t*)x, (int)(threadIdx.x & 63));
  const int seg = blockIdx.y;
  if (seg == 4) {
    if (blockIdx.x == 0 && threadIdx.x == 0) *flag = f32 ? 1 : 0;
    const int i = blockIdx.x * 256 + threadIdx.x;
    if (i >= 1024) return;
    const void* bs[3] = {bq, bk, bv};
#pragma unroll
    for (int k = 0; k < 3; ++k)
      biasf[k * 1024 + i] = f32 ? ((const float*)bs[k])[i] : bf2f(((const ushort_t*)bs[k])[i]);
    return;
  }
  const void* src = (seg == 0) ? x : (seg == 1) ? wq : (seg == 2) ? wk : wv;
  ushort_t* dst   = (seg == 0) ? xb : (seg == 1) ? wqb : (seg == 2) ? wkb : wvb;
  const int n = (seg == 0) ? 4194304 : 1048576;
  const int i = (blockIdx.x * 256 + threadIdx.x) * 8;
  if (i >= n) return;
  if (f32) {
    const float* s = (const float*)src + i;
    ushortx8 o;
#pragma unroll
    for (int j = 0; j < 8; ++j) o[j] = f2bf(s[j]);
    *(ushortx8*)(dst + i) = o;
  } else {
    *(ushortx8*)(dst + i) = *(const ushortx8*)((const ushort_t*)src + i);
  }
}

// ---------------------------------------------------------------------------
// QKV projection: out = x @ W^T + b; Q scaled by log2(e)/sqrt(64).
// which==2 (V) writes DIRECTLY in transposed layout Vt(bh,hs,s).
// ---------------------------------------------------------------------------
__global__ __launch_bounds__(256, 2) void qkv_gemm(
    const ushort_t* __restrict__ x,
    const ushort_t* __restrict__ Wq, const ushort_t* __restrict__ Wk,
    const ushort_t* __restrict__ Wv, const float* __restrict__ biasf,
    ushort_t* __restrict__ Qo, ushort_t* __restrict__ Ko, ushort_t* __restrict__ Vt)
{
  __shared__ __attribute__((aligned(16))) ushort_t As[128 * 32];
  __shared__ __attribute__((aligned(16))) ushort_t Bs[128 * 32];

  const int which = blockIdx.z;
  const ushort_t* W = (which == 0) ? Wq : (which == 1) ? Wk : Wv;
  const float oscale = (which == 0) ? 0.18033688011112042f : 1.0f;

  const int n0 = blockIdx.x * 128;
  const int m0 = blockIdx.y * 128;

  const int tid  = threadIdx.x;
  const int wave = tid >> 6;
  const int lane = tid & 63;
  const int ln   = lane & 15;
  const int quad = lane >> 4;
  const int wm = (wave >> 1) * 64;
  const int wn = (wave & 1) * 64;

  floatx4 acc[4][4];
#pragma unroll
  for (int i = 0; i < 4; ++i)
#pragma unroll
    for (int j = 0; j < 4; ++j) acc[i][j] = floatx4{0.f, 0.f, 0.f, 0.f};

  const int c1 = tid, c2 = tid + 256;
  const ushort_t* ga1 = x + (m0 + (c1 >> 2)) * 1024 + (c1 & 3) * 8;
  const ushort_t* ga2 = x + (m0 + (c2 >> 2)) * 1024 + (c2 & 3) * 8;
  const ushort_t* gb1 = W + (n0 + (c1 >> 2)) * 1024 + (c1 & 3) * 8;
  const ushort_t* gb2 = W + (n0 + (c2 >> 2)) * 1024 + (c2 & 3) * 8;
  ushort_t* la1 = As + wave * 512;
  ushort_t* la2 = As + 2048 + wave * 512;
  ushort_t* lb1 = Bs + wave * 512;
  ushort_t* lb2 = Bs + 2048 + wave * 512;

  for (int kt = 0; kt < 1024; kt += 32) {
    __syncthreads();
    load16_lds(ga1 + kt, la1);
    load16_lds(ga2 + kt, la2);
    load16_lds(gb1 + kt, lb1);
    load16_lds(gb2 + kt, lb2);
    __syncthreads();

    bf16x8 af[4], bfr[4];
#pragma unroll
    for (int mi = 0; mi < 4; ++mi)
      af[mi] = ldfrag(As + (wm + mi * 16 + ln) * 32 + quad * 8);
#pragma unroll
    for (int ni = 0; ni < 4; ++ni)
      bfr[ni] = ldfrag(Bs + (wn + ni * 16 + ln) * 32 + quad * 8);
#pragma unroll
    for (int mi = 0; mi < 4; ++mi)
#pragma unroll
      for (int ni = 0; ni < 4; ++ni)
        acc[mi][ni] = __builtin_amdgcn_mfma_f32_16x16x32_bf16(af[mi], bfr[ni], acc[mi][ni], 0, 0, 0);
  }

  float bvv[4];
#pragma unroll
  for (int ni = 0; ni < 4; ++ni) bvv[ni] = biasf[which * 1024 + n0 + wn + ni * 16 + ln];

  if (which == 2) {
#pragma unroll
    for (int mi = 0; mi < 4; ++mi)
#pragma unroll
      for (int ni = 0; ni < 4; ++ni) {
        const int col = n0 + wn + ni * 16 + ln;
        const int row0 = m0 + wm + mi * 16 + quad * 4;
        const int b = row0 >> 11, s0 = row0 & 2047;
        const int h = col >> 6, hs = col & 63;
        ushortx4 pk;
#pragma unroll
        for (int r = 0; r < 4; ++r) pk[r] = f2bf(acc[mi][ni][r] + bvv[ni]);
        *(ushortx4*)(Vt + ((size_t)((b * 16 + h) * 64 + hs)) * 2048 + s0) = pk;
      }
  } else {
    ushort_t* out = (which == 0) ? Qo : Ko;
#pragma unroll
    for (int mi = 0; mi < 4; ++mi)
#pragma unroll
      for (int ni = 0; ni < 4; ++ni) {
        const int col = n0 + wn + ni * 16 + ln;
#pragma unroll
        for (int r = 0; r < 4; ++r) {
          const int row = m0 + wm + mi * 16 + quad * 4 + r;
          out[row * 1024 + col] = f2bf((acc[mi][ni][r] + bvv[ni]) * oscale);
        }
      }
  }
}

// ---------------------------------------------------------------------------
// Flash attention v22 — v20 (LDS-shared K/V, counted pipeline, NO setprio)
// with THREE LDS buffer sets: one barrier + one counted vmcnt per tile, and
// the overwrite-guard comes free from the rotation:
//   prologue: STAGE(b0,t0); STAGE(b1,t1)
//   loop t:  vmcnt(4) [vmcnt(0) last] -> sched_barrier -> s_barrier
//              // own t-loads landed (t+1's 4 stay IN FLIGHT, T4 counted);
//              // all waves finished compute(t-1) -> its buffer is dead.
//            STAGE(b[(t+2)%3], t+2)   // overwrites t-1's buffer: safe
//            COMPUTE(b[t%3])          // t+2's loads land under this
// vs v20: barriers/tile 2->1, lgkmcnt(0) drains 1->0, prefetch ~2 tiles.
// vs v21 (regressed): no setprio (m190: negative in near-lockstep loops),
// prefetch distance restored.  LDS 48KB -> 3 blocks/CU (12 waves/CU, above
// the 7.6 avg observed in v21, so the cap shouldn't bind).
// Math/staging/swizzle/combine byte-identical to the passing v19/v20.
// ---------------------------------------------------------------------------
__global__ __launch_bounds__(256) void flash22(
    const ushort_t* __restrict__ Q, const ushort_t* __restrict__ Kx,
    const ushort_t* __restrict__ Vt, void* __restrict__ out,
    const int* __restrict__ flag)
{
  __shared__ __attribute__((aligned(16))) ushort_t Kl[3][4096];  // [buf][row64 x unit8 x 8el]
  __shared__ __attribute__((aligned(16))) ushort_t Vl[3][4096];  // rows = d, cols = kv

  const bool f32o = (*flag != 0);
  const int tid  = threadIdx.x;
  const int wave = tid >> 6;          // 0..3
  const int lane = tid & 63;
  const int l31 = lane & 31;
  const int hi  = lane >> 5;
  const int qsub = wave & 1;          // which 32 q-rows
  const int kvh  = wave >> 1;         // which 32-kv half of each tile

#define CROW(r) (((r) & 3) + 8 * ((r) >> 2) + 4 * hi)

  // XCD-swizzled, big-chunk-first: 1024 blocks = 32 bh x 32 chunks of 64 rows.
  const int i = blockIdx.x;
  const int xcd = i & 7, j = i >> 3;
  const int bh = xcd * 4 + (j & 3);
  const int cc = 31 - (j >> 2);        // q-chunk 0..31, big first
  const int b = bh >> 4, h = bh & 15;
  const int qblk = cc * 64;
  const int qw = qblk + 32 * qsub;     // this wave's first q row
  const int nt = cc + 1;               // 64-kv tiles staged by the block

  const ushort_t* kbase = Kx + ((size_t)b * 2048) * 1024 + h * 64;
  const ushort_t* vbase = Vt + (size_t)bh * 64 * 2048;

  // ---- staging geometry: per wave, 4 x global_load_lds (1KB each).
  // dest is linear (base + lane*16B); source unit is XOR-pre-swizzled so the
  // LDS image is LDS[row][u] = G[row][u ^ (row&7)] (rule #21 both-sides).
  const int srow = 8 * wave + (lane >> 3);            // row for chunk 0
  const int sus  = (lane & 7) ^ (lane >> 3);          // swizzled source unit
  const ushort_t* kp = kbase + (size_t)srow * 1024 + sus * 8;
  const ushort_t* vp = vbase + (size_t)srow * 2048 + sus * 8;

#define STAGE(BUFI, KV0) do {                                                 \
    const ushort_t* kp_ = kp + (size_t)(KV0) * 1024;                          \
    const ushort_t* vp_ = vp + (KV0);                                         \
    load16_lds(kp_,                     &Kl[BUFI][(wave << 6) * 8]);          \
    load16_lds(kp_ + 32 * 1024,         &Kl[BUFI][2048 + (wave << 6) * 8]);   \
    load16_lds(vp_,                     &Vl[BUFI][(wave << 6) * 8]);          \
    load16_lds(vp_ + (size_t)32 * 2048, &Vl[BUFI][2048 + (wave << 6) * 8]);   \
  } while (0)

  // Q as B-operand: n=q=l31, k = s*16 + hi*8 + j  (8 contiguous d per load)
  bf16x8 qf[4];
#pragma unroll
  for (int s = 0; s < 4; ++s)
    qf[s] = ldfrag(Q + (size_t)(b * 2048 + qw + l31) * 1024 + h * 64 + s * 16 + hi * 8);

  floatx16 ot[2];
#pragma unroll
  for (int dq = 0; dq < 2; ++dq)
#pragma unroll
    for (int r = 0; r < 16; ++r) ot[dq][r] = 0.f;
  float li = 0.f;

  const int swz = l31 & 7;            // read-side row&7 for K (krow) and V (vrow)

  // pack 8 p-values (one 16-kv step) and feed both d-quadrants
#define PACK_PV(BUFI, PARR, SH, KSTEP) do {                                   \
    unsigned X_ = cvtpk_bf16(PARR[8 * (SH) + 0], PARR[8 * (SH) + 1]);         \
    unsigned Y_ = cvtpk_bf16(PARR[8 * (SH) + 2], PARR[8 * (SH) + 3]);         \
    unsigned Z_ = cvtpk_bf16(PARR[8 * (SH) + 4], PARR[8 * (SH) + 5]);         \
    unsigned W_ = cvtpk_bf16(PARR[8 * (SH) + 6], PARR[8 * (SH) + 7]);         \
    plswap(X_, Z_);                                                           \
    plswap(Y_, W_);                                                           \
    uintx4 u_ = {X_, Y_, Z_, W_};                                             \
    const bf16x8 pa_ = __builtin_bit_cast(bf16x8, u_);                        \
    const bf16x8 v0_ = ldfrag(&Vl[BUFI][(l31) * 64 + ((2 * (KSTEP) + hi) ^ swz) * 8]);        \
    const bf16x8 v1_ = ldfrag(&Vl[BUFI][(32 + l31) * 64 + ((2 * (KSTEP) + hi) ^ swz) * 8]);   \
    ot[0] = __builtin_amdgcn_mfma_f32_32x32x16_bf16(pa_, v0_, ot[0], 0, 0, 0);\
    ot[1] = __builtin_amdgcn_mfma_f32_32x32x16_bf16(pa_, v1_, ot[1], 0, 0, 0);\
  } while (0)

  // this wave's 32-kv half of tile at kv0: S-MFMA -> mask/exp -> li -> PV
#define COMPUTE(BUFI, KV0) do {                                               \
    const int krow_ = 32 * kvh + l31;                                         \
    bf16x8 kf0_ = ldfrag(&Kl[BUFI][krow_ * 64 + ((0 + hi) ^ swz) * 8]);       \
    bf16x8 kf1_ = ldfrag(&Kl[BUFI][krow_ * 64 + ((2 + hi) ^ swz) * 8]);       \
    bf16x8 kf2_ = ldfrag(&Kl[BUFI][krow_ * 64 + ((4 + hi) ^ swz) * 8]);       \
    bf16x8 kf3_ = ldfrag(&Kl[BUFI][krow_ * 64 + ((6 + hi) ^ swz) * 8]);       \
    floatx16 st_;                                                             \
    _Pragma("unroll")                                                         \
    for (int r = 0; r < 16; ++r) st_[r] = 0.f;                                \
    st_ = __builtin_amdgcn_mfma_f32_32x32x16_bf16(kf0_, qf[0], st_, 0, 0, 0); \
    st_ = __builtin_amdgcn_mfma_f32_32x32x16_bf16(kf1_, qf[1], st_, 0, 0, 0); \
    st_ = __builtin_amdgcn_mfma_f32_32x32x16_bf16(kf2_, qf[2], st_, 0, 0, 0); \
    st_ = __builtin_amdgcn_mfma_f32_32x32x16_bf16(kf3_, qf[3], st_, 0, 0, 0); \
    const int kvb_ = (KV0) + 32 * kvh;                                        \
    float p_[16];                                                             \
    if (kvb_ + 31 > qw) {                                                     \
      const int qg_ = qw + l31;                                               \
      _Pragma("unroll")                                                       \
      for (int r = 0; r < 16; ++r) {                                          \
        const int kva_ = kvb_ + CROW(r);                                      \
        const float e_ = __builtin_amdgcn_exp2f(st_[r]);                      \
        p_[r] = (kva_ > qg_) ? 0.f : e_;                                      \
      }                                                                       \
    } else {                                                                  \
      _Pragma("unroll")                                                       \
      for (int r = 0; r < 16; ++r) p_[r] = __builtin_amdgcn_exp2f(st_[r]);    \
    }                                                                         \
    float ls_ = 0.f;                                                          \
    _Pragma("unroll")                                                         \
    for (int r = 0; r < 16; ++r) ls_ += p_[r];                                \
    li += ls_;                                                                \
    PACK_PV(BUFI, p_, 0, 2 * kvh + 0);                                        \
    PACK_PV(BUFI, p_, 1, 2 * kvh + 1);                                        \
  } while (0)

  // ---- main loop: ONE barrier + one COUNTED vmcnt per tile, 3-buffer ----
  STAGE(0, 0);
  if (nt > 1) STAGE(1, 64);
  int bcur = 0;
  for (int t = 0; t < nt; ++t) {
    // own tile-t loads landed; tile-(t+1)'s 4 loads stay in flight (T4)
    if (t + 1 >= nt) {
      asm volatile("s_waitcnt vmcnt(0)" ::: "memory");
    } else {
      asm volatile("s_waitcnt vmcnt(4)" ::: "memory");
    }
    __builtin_amdgcn_sched_barrier(0);
    __builtin_amdgcn_s_barrier();
    // after barrier: all waves' t-loads landed; everyone done with t-1's
    // buffer -> b[(t+2)%3] (== b[(t-1)%3]) is safe to overwrite.
    const int bn2 = (bcur >= 1) ? (bcur - 1) : 2;   // (bcur+2)%3
    if (t + 2 < nt) STAGE(bn2, (t + 2) * 64);
    const int kv0 = t * 64;
    if (kv0 + 32 * kvh <= qw + 31) COMPUTE(bcur, kv0);
    bcur = (bcur >= 2) ? 0 : (bcur + 1);            // (bcur+1)%3
  }

#undef STAGE
#undef PACK_PV
#undef COMPUTE

  // finalize li: lane l and l^32 hold complementary kv rows of the same q
  float lf = li + __shfl_xor(li, 32);

  // waves finish compute at different times; sync before reusing K/V LDS
  __syncthreads();

  // ---- kv-half combine through dead K/V LDS ----
  float* Sc = (float*)&Kl[0][0];   // 4096 floats: [qsub][32 q][64 d]
  float* Lc = (float*)&Vl[0][0];   // [0..63] li sums, [64..127] 1/li
  if (kvh == 1) {
#pragma unroll
    for (int dq = 0; dq < 2; ++dq)
#pragma unroll
      for (int r = 0; r < 16; ++r)
        Sc[qsub * 2048 + CROW(r) * 64 + 32 * dq + l31] = ot[dq][r];
    Lc[qsub * 32 + l31] = lf;      // both hi-halves write the same value
  }
  __syncthreads();
  if (kvh == 0) {
#pragma unroll
    for (int dq = 0; dq < 2; ++dq)
#pragma unroll
      for (int r = 0; r < 16; ++r)
        ot[dq][r] += Sc[qsub * 2048 + CROW(r) * 64 + 32 * dq + l31];
    lf += Lc[qsub * 32 + l31];
    Lc[64 + qsub * 32 + l31] = 1.0f / lf;

#pragma unroll
    for (int r = 0; r < 16; ++r) {
      const int q_ = qw + CROW(r);
      const float iv = Lc[64 + qsub * 32 + CROW(r)];
      if (f32o) {
        float* of = (float*)out;
#pragma unroll
        for (int dq = 0; dq < 2; ++dq)
          of[(size_t)(b * 2048 + q_) * 1024 + h * 64 + 32 * dq + l31] = ot[dq][r] * iv;
      } else {
        ushort_t* ob = (ushort_t*)out;
#pragma unroll
        for (int dq = 0; dq < 2; ++dq)
          ob[(size_t)(b * 2048 + q_) * 1024 + h * 64 + 32 * dq + l31] = f2bf(ot[dq][r] * iv);
      }
    }
  }
#undef CROW
}

// ---------------------------------------------------------------------------
extern "C" void kernel_launch(void* const* d_in, const int* in_sizes, int n_in,
                              void* d_out, int out_size, void* d_ws, size_t ws_size,
                              hipStream_t stream) {
  char* w = (char*)d_ws;
  int* flag = (int*)w;
  size_t off = 256;
  ushort_t* xb  = (ushort_t*)(w + off); off += (size_t)4194304 * 2;
  ushort_t* wqb = (ushort_t*)(w + off); off += (size_t)1048576 * 2;
  ushort_t* wkb = (ushort_t*)(w + off); off += (size_t)1048576 * 2;
  ushort_t* wvb = (ushort_t*)(w + off); off += (size_t)1048576 * 2;
  float* biasf  = (float*)(w + off);    off += (size_t)3 * 1024 * 4;
  ushort_t* Qw  = (ushort_t*)(w + off); off += (size_t)4194304 * 2;
  ushort_t* Kw  = (ushort_t*)(w + off); off += (size_t)4194304 * 2;
  ushort_t* Vtw = (ushort_t*)(w + off);

  convert_all<<<dim3(2048, 5), 256, 0, stream>>>(
      d_in[0], d_in[1], d_in[3], d_in[5], d_in[2], d_in[4], d_in[6],
      xb, wqb, wkb, wvb, biasf, flag);
  qkv_gemm<<<dim3(8, 32, 3), 256, 0, stream>>>(xb, wqb, wkb, wvb, biasf, Qw, Kw, Vtw);
  flash22<<<1024, 256, 0, stream>>>(Qw, Kw, Vtw, d_out, flag);
}

// Round 15
// 148.612 us; speedup vs baseline: 1.0464x; 1.0441x over previous
//
#include <hip/hip_runtime.h>

typedef unsigned short ushort_t;
typedef __bf16 bf16x8 __attribute__((ext_vector_type(8)));
typedef unsigned short ushortx8 __attribute__((ext_vector_type(8)));
typedef unsigned short ushortx4 __attribute__((ext_vector_type(4)));
typedef unsigned int uintx4 __attribute__((ext_vector_type(4)));
typedef float floatx4 __attribute__((ext_vector_type(4)));
typedef float floatx16 __attribute__((ext_vector_type(16)));

__device__ inline void load16_lds(const ushort_t* g, ushort_t* l) {
  __builtin_amdgcn_global_load_lds(
      (__attribute__((address_space(1))) void*)(g),
      (__attribute__((address_space(3))) void*)(l),
      16, 0, 0);
}

__device__ inline float bf2f(ushort_t u) {
  unsigned int v = ((unsigned int)u) << 16;
  return __builtin_bit_cast(float, v);
}

__device__ inline ushort_t f2bf(float f) {
  unsigned int u = __builtin_bit_cast(unsigned int, f);
  u += 0x7fffu + ((u >> 16) & 1u);
  return (ushort_t)(u >> 16);
}

__device__ inline bf16x8 ldfrag(const ushort_t* p) {
  return __builtin_bit_cast(bf16x8, *(const ushortx8*)p);
}

// pack two f32 -> one u32 of 2 bf16 (lo = first arg); no builtin on gfx950.
__device__ inline unsigned cvtpk_bf16(float lo, float hi) {
  unsigned r;
  asm("v_cvt_pk_bf16_f32 %0, %1, %2" : "=v"(r) : "v"(lo), "v"(hi));
  return r;
}

// exchange one 32-lane half of a with the complementary half of b
// (HK/m214-v22 arg order; verified on HW with the same crow layout).
__device__ inline void plswap(unsigned& a, unsigned& b) {
  asm("v_permlane32_swap_b32 %0, %1" : "+v"(a), "+v"(b));
}

// per-wave dtype sniff; P(wrong | fp32) ~= 0.55^64 ~= 4e-17.
__device__ inline bool sniff_f32(const ushort_t* x, int lane_off) {
  float v = fabsf(bf2f(x[lane_off]));
  bool big = !(v < 1e4f);
  return __ballot(big) != 0ull;
}

// ---------------------------------------------------------------------------
// Canonicalize inputs to bf16 (x, Wq, Wk, Wv) and fp32 biases; inline sniff.
// ---------------------------------------------------------------------------
__global__ __launch_bounds__(256) void convert_all(
    const void* __restrict__ x,
    const void* __restrict__ wq, const void* __restrict__ wk, const void* __restrict__ wv,
    const void* __restrict__ bq, const void* __restrict__ bk, const void* __restrict__ bv,
    ushort_t* __restrict__ xb, ushort_t* __restrict__ wqb,
    ushort_t* __restrict__ wkb, ushort_t* __restrict__ wvb,
    float* __restrict__ biasf, int* __restrict__ flag)
{
  const bool f32 = sniff_f32((const ushort_t*)x, (int)(threadIdx.x & 63));
  const int seg = blockIdx.y;
  if (seg == 4) {
    if (blockIdx.x == 0 && threadIdx.x == 0) *flag = f32 ? 1 : 0;
    const int i = blockIdx.x * 256 + threadIdx.x;
    if (i >= 1024) return;
    const void* bs[3] = {bq, bk, bv};
#pragma unroll
    for (int k = 0; k < 3; ++k)
      biasf[k * 1024 + i] = f32 ? ((const float*)bs[k])[i] : bf2f(((const ushort_t*)bs[k])[i]);
    return;
  }
  const void* src = (seg == 0) ? x : (seg == 1) ? wq : (seg == 2) ? wk : wv;
  ushort_t* dst   = (seg == 0) ? xb : (seg == 1) ? wqb : (seg == 2) ? wkb : wvb;
  const int n = (seg == 0) ? 4194304 : 1048576;
  const int i = (blockIdx.x * 256 + threadIdx.x) * 8;
  if (i >= n) return;
  if (f32) {
    const float* s = (const float*)src + i;
    ushortx8 o;
#pragma unroll
    for (int j = 0; j < 8; ++j) o[j] = f2bf(s[j]);
    *(ushortx8*)(dst + i) = o;
  } else {
    *(ushortx8*)(dst + i) = *(const ushortx8*)((const ushort_t*)src + i);
  }
}

// ---------------------------------------------------------------------------
// QKV projection v2: out = x @ W^T + b; Q scaled by log2(e)/sqrt(64).
// which==2 (V) writes DIRECTLY in transposed layout Vt(bh,hs,s).
// vs v1 (m97 128²/BK=32 shell): (1) BK=64 -> barrier+drain events halve
// (16 K-steps instead of 32); (2) LDS tiles [128][64] XOR-swizzled
// (unit ^= row&7; pre-swizzled GLOBAL source + swizzled ds_read — the
// rule-#21 both-sides pattern verified in flash19/20) -> ds_read_b128
// aliasing 16->8-way; (3) __launch_bounds__(256,3) caps VGPR ~170 so the
// 768-block grid runs 3 blocks/CU (m97's measured-best occupancy).
// Math identical to v1 (two 32-K MFMA steps per 64-K tile).
// ---------------------------------------------------------------------------
__global__ __launch_bounds__(256, 3) void qkv_gemm(
    const ushort_t* __restrict__ x,
    const ushort_t* __restrict__ Wq, const ushort_t* __restrict__ Wk,
    const ushort_t* __restrict__ Wv, const float* __restrict__ biasf,
    ushort_t* __restrict__ Qo, ushort_t* __restrict__ Ko, ushort_t* __restrict__ Vt)
{
  __shared__ __attribute__((aligned(16))) ushort_t As[128 * 64];
  __shared__ __attribute__((aligned(16))) ushort_t Bs[128 * 64];

  const int which = blockIdx.z;
  const ushort_t* W = (which == 0) ? Wq : (which == 1) ? Wk : Wv;
  const float oscale = (which == 0) ? 0.18033688011112042f : 1.0f;

  const int n0 = blockIdx.x * 128;
  const int m0 = blockIdx.y * 128;

  const int tid  = threadIdx.x;
  const int wave = tid >> 6;
  const int lane = tid & 63;
  const int ln   = lane & 15;
  const int quad = lane >> 4;
  const int wm = (wave >> 1) * 64;
  const int wn = (wave & 1) * 64;

  floatx4 acc[4][4];
#pragma unroll
  for (int i = 0; i < 4; ++i)
#pragma unroll
    for (int j = 0; j < 4; ++j) acc[i][j] = floatx4{0.f, 0.f, 0.f, 0.f};

  // staging: tiles are [128 rows][8 units of 8 ushorts], LDS image
  // LDS[r][u] = G[r][u ^ (r&7)].  chunk c = i*256+tid -> r = 32i + (tid>>3),
  // u = tid&7; r&7 = (tid>>3)&7 for all i (32i = 0 mod 8).
  const int r0 = tid >> 3;
  const int su = (tid & 7) ^ (r0 & 7);           // pre-swizzled source unit
  const ushort_t* ga = x + (size_t)(m0 + r0) * 1024 + su * 8;
  const ushort_t* gb = W + (size_t)(n0 + r0) * 1024 + su * 8;

  for (int kt = 0; kt < 1024; kt += 64) {
    __syncthreads();
#pragma unroll
    for (int i = 0; i < 4; ++i) {
      load16_lds(ga + (size_t)(32 * i) * 1024 + kt, As + (i * 256 + tid) * 8);
      load16_lds(gb + (size_t)(32 * i) * 1024 + kt, Bs + (i * 256 + tid) * 8);
    }
    __syncthreads();

#pragma unroll
    for (int ks = 0; ks < 2; ++ks) {
      bf16x8 af[4], bfr[4];
#pragma unroll
      for (int mi = 0; mi < 4; ++mi) {
        const int row = wm + mi * 16 + ln;
        af[mi] = ldfrag(As + row * 64 + (((ks << 2) + quad) ^ (row & 7)) * 8);
      }
#pragma unroll
      for (int ni = 0; ni < 4; ++ni) {
        const int row = wn + ni * 16 + ln;
        bfr[ni] = ldfrag(Bs + row * 64 + (((ks << 2) + quad) ^ (row & 7)) * 8);
      }
#pragma unroll
      for (int mi = 0; mi < 4; ++mi)
#pragma unroll
        for (int ni = 0; ni < 4; ++ni)
          acc[mi][ni] = __builtin_amdgcn_mfma_f32_16x16x32_bf16(af[mi], bfr[ni], acc[mi][ni], 0, 0, 0);
    }
  }

  float bvv[4];
#pragma unroll
  for (int ni = 0; ni < 4; ++ni) bvv[ni] = biasf[which * 1024 + n0 + wn + ni * 16 + ln];

  if (which == 2) {
#pragma unroll
    for (int mi = 0; mi < 4; ++mi)
#pragma unroll
      for (int ni = 0; ni < 4; ++ni) {
        const int col = n0 + wn + ni * 16 + ln;
        const int row0 = m0 + wm + mi * 16 + quad * 4;
        const int b = row0 >> 11, s0 = row0 & 2047;
        const int h = col >> 6, hs = col & 63;
        ushortx4 pk;
#pragma unroll
        for (int r = 0; r < 4; ++r) pk[r] = f2bf(acc[mi][ni][r] + bvv[ni]);
        *(ushortx4*)(Vt + ((size_t)((b * 16 + h) * 64 + hs)) * 2048 + s0) = pk;
      }
  } else {
    ushort_t* out = (which == 0) ? Qo : Ko;
#pragma unroll
    for (int mi = 0; mi < 4; ++mi)
#pragma unroll
      for (int ni = 0; ni < 4; ++ni) {
        const int col = n0 + wn + ni * 16 + ln;
#pragma unroll
        for (int r = 0; r < 4; ++r) {
          const int row = m0 + wm + mi * 16 + quad * 4 + r;
          out[row * 1024 + col] = f2bf((acc[mi][ni][r] + bvv[ni]) * oscale);
        }
      }
  }
}

// ---------------------------------------------------------------------------
// Flash attention v20 (VERBATIM revert — best total 151.3us): LDS-shared K/V,
// 4-wave split, counted-vmcnt double-buffer pipeline:
//   prologue: STAGE(buf0,t0); STAGE(buf1,t1)
//   loop:  vmcnt(4) [vmcnt(0) last tile] -> barrier
//          COMPUTE(cur)
//          lgkmcnt(0) -> barrier
//          STAGE(cur, t+2)
// ---------------------------------------------------------------------------
__global__ __launch_bounds__(256) void flash20(
    const ushort_t* __restrict__ Q, const ushort_t* __restrict__ Kx,
    const ushort_t* __restrict__ Vt, void* __restrict__ out,
    const int* __restrict__ flag)
{
  __shared__ __attribute__((aligned(16))) ushort_t Kl[2][4096];  // [buf][row64 x unit8 x 8el]
  __shared__ __attribute__((aligned(16))) ushort_t Vl[2][4096];  // rows = d, cols = kv

  const bool f32o = (*flag != 0);
  const int tid  = threadIdx.x;
  const int wave = tid >> 6;          // 0..3
  const int lane = tid & 63;
  const int l31 = lane & 31;
  const int hi  = lane >> 5;
  const int qsub = wave & 1;          // which 32 q-rows
  const int kvh  = wave >> 1;         // which 32-kv half of each tile

#define CROW(r) (((r) & 3) + 8 * ((r) >> 2) + 4 * hi)

  // XCD-swizzled, big-chunk-first: 1024 blocks = 32 bh x 32 chunks of 64 rows.
  const int i = blockIdx.x;
  const int xcd = i & 7, j = i >> 3;
  const int bh = xcd * 4 + (j & 3);
  const int cc = 31 - (j >> 2);        // q-chunk 0..31, big first
  const int b = bh >> 4, h = bh & 15;
  const int qblk = cc * 64;
  const int qw = qblk + 32 * qsub;     // this wave's first q row
  const int nt = cc + 1;               // 64-kv tiles staged by the block

  const ushort_t* kbase = Kx + ((size_t)b * 2048) * 1024 + h * 64;
  const ushort_t* vbase = Vt + (size_t)bh * 64 * 2048;

  // ---- staging geometry: per wave, 4 x global_load_lds (1KB each).
  // dest is linear (base + lane*16B); source unit is XOR-pre-swizzled so the
  // LDS image is LDS[row][u] = G[row][u ^ (row&7)] (rule #21 both-sides).
  const int srow = 8 * wave + (lane >> 3);            // row for chunk 0
  const int sus  = (lane & 7) ^ (lane >> 3);          // swizzled source unit
  const ushort_t* kp = kbase + (size_t)srow * 1024 + sus * 8;
  const ushort_t* vp = vbase + (size_t)srow * 2048 + sus * 8;

#define STAGE(BUFI, KV0) do {                                                 \
    const ushort_t* kp_ = kp + (size_t)(KV0) * 1024;                          \
    const ushort_t* vp_ = vp + (KV0);                                         \
    load16_lds(kp_,                     &Kl[BUFI][(wave << 6) * 8]);          \
    load16_lds(kp_ + 32 * 1024,         &Kl[BUFI][2048 + (wave << 6) * 8]);   \
    load16_lds(vp_,                     &Vl[BUFI][(wave << 6) * 8]);          \
    load16_lds(vp_ + (size_t)32 * 2048, &Vl[BUFI][2048 + (wave << 6) * 8]);   \
  } while (0)

  // Q as B-operand: n=q=l31, k = s*16 + hi*8 + j  (8 contiguous d per load)
  bf16x8 qf[4];
#pragma unroll
  for (int s = 0; s < 4; ++s)
    qf[s] = ldfrag(Q + (size_t)(b * 2048 + qw + l31) * 1024 + h * 64 + s * 16 + hi * 8);

  floatx16 ot[2];
#pragma unroll
  for (int dq = 0; dq < 2; ++dq)
#pragma unroll
    for (int r = 0; r < 16; ++r) ot[dq][r] = 0.f;
  float li = 0.f;

  const int swz = l31 & 7;            // read-side row&7 for K (krow) and V (vrow)

  // pack 8 p-values (one 16-kv step) and feed both d-quadrants
#define PACK_PV(BUFI, PARR, SH, KSTEP) do {                                   \
    unsigned X_ = cvtpk_bf16(PARR[8 * (SH) + 0], PARR[8 * (SH) + 1]);         \
    unsigned Y_ = cvtpk_bf16(PARR[8 * (SH) + 2], PARR[8 * (SH) + 3]);         \
    unsigned Z_ = cvtpk_bf16(PARR[8 * (SH) + 4], PARR[8 * (SH) + 5]);         \
    unsigned W_ = cvtpk_bf16(PARR[8 * (SH) + 6], PARR[8 * (SH) + 7]);         \
    plswap(X_, Z_);                                                           \
    plswap(Y_, W_);                                                           \
    uintx4 u_ = {X_, Y_, Z_, W_};                                             \
    const bf16x8 pa_ = __builtin_bit_cast(bf16x8, u_);                        \
    const bf16x8 v0_ = ldfrag(&Vl[BUFI][(l31) * 64 + ((2 * (KSTEP) + hi) ^ swz) * 8]);        \
    const bf16x8 v1_ = ldfrag(&Vl[BUFI][(32 + l31) * 64 + ((2 * (KSTEP) + hi) ^ swz) * 8]);   \
    ot[0] = __builtin_amdgcn_mfma_f32_32x32x16_bf16(pa_, v0_, ot[0], 0, 0, 0);\
    ot[1] = __builtin_amdgcn_mfma_f32_32x32x16_bf16(pa_, v1_, ot[1], 0, 0, 0);\
  } while (0)

  // this wave's 32-kv half of tile at kv0: S-MFMA -> mask/exp -> li -> PV
#define COMPUTE(BUFI, KV0) do {                                               \
    const int krow_ = 32 * kvh + l31;                                         \
    bf16x8 kf0_ = ldfrag(&Kl[BUFI][krow_ * 64 + ((0 + hi) ^ swz) * 8]);       \
    bf16x8 kf1_ = ldfrag(&Kl[BUFI][krow_ * 64 + ((2 + hi) ^ swz) * 8]);       \
    bf16x8 kf2_ = ldfrag(&Kl[BUFI][krow_ * 64 + ((4 + hi) ^ swz) * 8]);       \
    bf16x8 kf3_ = ldfrag(&Kl[BUFI][krow_ * 64 + ((6 + hi) ^ swz) * 8]);       \
    floatx16 st_;                                                             \
    _Pragma("unroll")                                                         \
    for (int r = 0; r < 16; ++r) st_[r] = 0.f;                                \
    st_ = __builtin_amdgcn_mfma_f32_32x32x16_bf16(kf0_, qf[0], st_, 0, 0, 0); \
    st_ = __builtin_amdgcn_mfma_f32_32x32x16_bf16(kf1_, qf[1], st_, 0, 0, 0); \
    st_ = __builtin_amdgcn_mfma_f32_32x32x16_bf16(kf2_, qf[2], st_, 0, 0, 0); \
    st_ = __builtin_amdgcn_mfma_f32_32x32x16_bf16(kf3_, qf[3], st_, 0, 0, 0); \
    const int kvb_ = (KV0) + 32 * kvh;                                        \
    float p_[16];                                                             \
    if (kvb_ + 31 > qw) {                                                     \
      const int qg_ = qw + l31;                                               \
      _Pragma("unroll")                                                       \
      for (int r = 0; r < 16; ++r) {                                          \
        const int kva_ = kvb_ + CROW(r);                                      \
        const float e_ = __builtin_amdgcn_exp2f(st_[r]);                      \
        p_[r] = (kva_ > qg_) ? 0.f : e_;                                      \
      }                                                                       \
    } else {                                                                  \
      _Pragma("unroll")                                                       \
      for (int r = 0; r < 16; ++r) p_[r] = __builtin_amdgcn_exp2f(st_[r]);    \
    }                                                                         \
    float ls_ = 0.f;                                                          \
    _Pragma("unroll")                                                         \
    for (int r = 0; r < 16; ++r) ls_ += p_[r];                                \
    li += ls_;                                                                \
    PACK_PV(BUFI, p_, 0, 2 * kvh + 0);                                        \
    PACK_PV(BUFI, p_, 1, 2 * kvh + 1);                                        \
  } while (0)

  // ---- main loop: counted-vmcnt pipeline, 2 raw barriers per tile ----
  int cur = 0;
  STAGE(0, 0);
  if (nt > 1) STAGE(1, 64);
  for (int t = 0; t < nt; ++t) {
    // wait for tile t's 4 staging loads only; tile t+1's stay in flight
    if (t == nt - 1) {
      asm volatile("s_waitcnt vmcnt(0)" ::: "memory");
    } else {
      asm volatile("s_waitcnt vmcnt(4)" ::: "memory");
    }
    __builtin_amdgcn_sched_barrier(0);
    __builtin_amdgcn_s_barrier();

    const int kv0 = t * 64;
    if (kv0 + 32 * kvh <= qw + 31) COMPUTE(cur, kv0);

    // all of this wave's LDS reads done; then block-wide ready to overwrite
    asm volatile("s_waitcnt lgkmcnt(0)" ::: "memory");
    __builtin_amdgcn_sched_barrier(0);
    __builtin_amdgcn_s_barrier();

    if (t + 2 < nt) STAGE(cur, (t + 2) * 64);
    cur ^= 1;
  }

#undef STAGE
#undef PACK_PV
#undef COMPUTE

  // finalize li: lane l and l^32 hold complementary kv rows of the same q
  float lf = li + __shfl_xor(li, 32);

  // ---- kv-half combine through dead K/V LDS (all loads retired: last tile
  // waited vmcnt(0); last barrier passed) ----
  float* Sc = (float*)&Kl[0][0];   // 4096 floats: [qsub][32 q][64 d]
  float* Lc = (float*)&Vl[0][0];   // [0..63] li sums, [64..127] 1/li
  if (kvh == 1) {
#pragma unroll
    for (int dq = 0; dq < 2; ++dq)
#pragma unroll
      for (int r = 0; r < 16; ++r)
        Sc[qsub * 2048 + CROW(r) * 64 + 32 * dq + l31] = ot[dq][r];
    Lc[qsub * 32 + l31] = lf;      // both hi-halves write the same value
  }
  __syncthreads();
  if (kvh == 0) {
#pragma unroll
    for (int dq = 0; dq < 2; ++dq)
#pragma unroll
      for (int r = 0; r < 16; ++r)
        ot[dq][r] += Sc[qsub * 2048 + CROW(r) * 64 + 32 * dq + l31];
    lf += Lc[qsub * 32 + l31];
    Lc[64 + qsub * 32 + l31] = 1.0f / lf;

#pragma unroll
    for (int r = 0; r < 16; ++r) {
      const int q_ = qw + CROW(r);
      const float iv = Lc[64 + qsub * 32 + CROW(r)];
      if (f32o) {
        float* of = (float*)out;
#pragma unroll
        for (int dq = 0; dq < 2; ++dq)
          of[(size_t)(b * 2048 + q_) * 1024 + h * 64 + 32 * dq + l31] = ot[dq][r] * iv;
      } else {
        ushort_t* ob = (ushort_t*)out;
#pragma unroll
        for (int dq = 0; dq < 2; ++dq)
          ob[(size_t)(b * 2048 + q_) * 1024 + h * 64 + 32 * dq + l31] = f2bf(ot[dq][r] * iv);
      }
    }
  }
#undef CROW
}

// ---------------------------------------------------------------------------
extern "C" void kernel_launch(void* const* d_in, const int* in_sizes, int n_in,
                              void* d_out, int out_size, void* d_ws, size_t ws_size,
                              hipStream_t stream) {
  char* w = (char*)d_ws;
  int* flag = (int*)w;
  size_t off = 256;
  ushort_t* xb  = (ushort_t*)(w + off); off += (size_t)4194304 * 2;
  ushort_t* wqb = (ushort_t*)(w + off); off += (size_t)1048576 * 2;
  ushort_t* wkb = (ushort_t*)(w + off); off += (size_t)1048576 * 2;
  ushort_t* wvb = (ushort_t*)(w + off); off += (size_t)1048576 * 2;
  float* biasf  = (float*)(w + off);    off += (size_t)3 * 1024 * 4;
  ushort_t* Qw  = (ushort_t*)(w + off); off += (size_t)4194304 * 2;
  ushort_t* Kw  = (ushort_t*)(w + off); off += (size_t)4194304 * 2;
  ushort_t* Vtw = (ushort_t*)(w + off);

  convert_all<<<dim3(2048, 5), 256, 0, stream>>>(
      d_in[0], d_in[1], d_in[3], d_in[5], d_in[2], d_in[4], d_in[6],
      xb, wqb, wkb, wvb, biasf, flag);
  qkv_gemm<<<dim3(8, 32, 3), 256, 0, stream>>>(xb, wqb, wkb, wvb, biasf, Qw, Kw, Vtw);
  flash20<<<1024, 256, 0, stream>>>(Qw, Kw, Vtw, d_out, flag);
}